// Round 5
// baseline (341.195 us; speedup 1.0000x reference)
//
#include <hip/hip_runtime.h>
#include <hip/hip_bf16.h>
#include <stdint.h>

#define S_SZ 4096
// (1/sqrt(256)) * log2(e): scores come out in exp2 domain
#define SCL 0.09016844005586937f

typedef short bf16x8 __attribute__((ext_vector_type(8)));
typedef float f32x4 __attribute__((ext_vector_type(4)));
typedef unsigned short u16;

#define MFMA16(a,b,c) __builtin_amdgcn_mfma_f32_16x16x32_bf16(a,b,c,0,0,0)

__device__ __forceinline__ u16 f2bf(float f){
    union { float f; uint32_t u; } v; v.f = f;
    return (u16)((v.u + 0x7FFFu + ((v.u >> 16) & 1u)) >> 16);
}

__device__ __forceinline__ void async16(const void* g, void* l){
    __builtin_amdgcn_global_load_lds(
        (const __attribute__((address_space(1))) unsigned int*)g,
        (__attribute__((address_space(3))) unsigned int*)l, 16, 0, 0);
}

// ---------------- weight transpose + cast: Wt[p][dout][din] = bf16(W[din][dout]) -----------
__global__ void wconv_kernel(const float* __restrict__ Wq, const float* __restrict__ Wk,
                             const float* __restrict__ Wv, u16* __restrict__ Wt){
    int idx = blockIdx.x*256 + threadIdx.x;       // 0..196607
    int p = idx >> 16; int rem = idx & 65535;
    int dout = rem >> 8, din = rem & 255;
    const float* W = (p==0) ? Wq : ((p==1) ? Wk : Wv);
    Wt[idx] = f2bf(W[din*256 + dout]);
}

// ---------------- projection GEMM: Out = bf16((X @ W + b) * scale) --------------------------
// mode 0: row-major [row][256]   mode 1: V grouped-transposed [b][s>>3][256][s&7]
__global__ void proj_kernel(const float* __restrict__ X, const u16* __restrict__ Wt,
                            const float* __restrict__ bias, u16* __restrict__ Out,
                            float scale, int mode){
    int w = threadIdx.x >> 6, lane = threadIdx.x & 63;
    int lr = lane & 15, lg = lane >> 4;
    int r0 = blockIdx.x * 64 + w * 16;            // this wave's 16 rows

    bf16x8 a[8];
    #pragma unroll
    for (int ks = 0; ks < 8; ++ks){
        const float* src = X + (size_t)(r0 + lr)*256 + ks*32 + lg*8;
        float4 f0 = *(const float4*)src;
        float4 f1 = *(const float4*)(src+4);
        bf16x8 t;
        t[0]=f2bf(f0.x); t[1]=f2bf(f0.y); t[2]=f2bf(f0.z); t[3]=f2bf(f0.w);
        t[4]=f2bf(f1.x); t[5]=f2bf(f1.y); t[6]=f2bf(f1.z); t[7]=f2bf(f1.w);
        a[ks]=t;
    }
    #pragma unroll
    for (int dt = 0; dt < 16; ++dt){
        f32x4 acc = {0.f,0.f,0.f,0.f};
        #pragma unroll
        for (int ks = 0; ks < 8; ++ks){
            bf16x8 b = *(const bf16x8*)(Wt + (size_t)(dt*16 + lr)*256 + ks*32 + lg*8);
            acc = MFMA16(a[ks], b, acc);
        }
        float bv = bias[dt*16 + lr];
        if (mode == 0){
            #pragma unroll
            for (int r = 0; r < 4; ++r){
                int row = r0 + lg*4 + r;
                Out[(size_t)row*256 + dt*16 + lr] = f2bf((acc[r] + bv)*scale);
            }
        } else {
            int row = r0 + lg*4;                  // 4 consecutive s rows
            int bb = row >> 12;
            int s  = row & 4095;
            ushort4 pk;
            pk.x = f2bf(acc[0]+bv); pk.y = f2bf(acc[1]+bv);
            pk.z = f2bf(acc[2]+bv); pk.w = f2bf(acc[3]+bv);
            u16* dst = Out + (size_t)bb*1048576 + (size_t)(s>>3)*2048 + (dt*16+lr)*8 + (s&7);
            *(ushort4*)dst = pk;
        }
    }
}

// ---------------- flash attention, kv-split partials ---------------------------------------
// grid 512, XCD-aware: xcd=bid&7 hosts 2 (bb,split) combos x 32 q-blocks
// block 256 thr = 4 waves x 32 q rows; Q frags in regs; K chunk 32 dbuf in LDS;
// V read DIRECT from L2 (grouped layout, coalesced); P per-wave in LDS.
// Softmax: per-lane running sum (no per-chunk shuffles); cross-lane max reduce
// only on the rare (> m+8) trigger.
#define CH_ROWS 32
#define NCH     32          /* 1024 kv rows per split / 32 */
#define P_STRIDE 72

__global__ __launch_bounds__(256, 2)
void attn_kernel(const u16* __restrict__ Qb, const u16* __restrict__ Kb,
                 const u16* __restrict__ Vt, float* __restrict__ Opart,
                 float* __restrict__ Mpart, float* __restrict__ Lpart){
    __shared__ char lds[43008];                   // K dbuf 32KB | P 10KB
    // layout: K0 @0, K1 @16384, P @32768
    char* Plds = lds + 32768;

    int tid = threadIdx.x;
    int w = tid >> 6, lane = tid & 63;
    int lr = lane & 15, lg = lane >> 4;

    // XCD-aware decode: same (bb,split) combo stays on one XCD for L2 reuse
    int bid = blockIdx.x;
    int xcd = bid & 7;
    int loc = bid >> 3;                 // 0..63
    int combo = xcd*2 + (loc >> 5);     // 0..15
    int qb = loc & 31;
    int bb = combo >> 2;
    int split = combo & 3;
    int qrow0 = qb*128 + w*32;

    const u16* Qbase = Qb + (size_t)bb*S_SZ*256;
    const u16* Kbase = Kb + (size_t)bb*S_SZ*256;
    const u16* Vbase = Vt + (size_t)bb*S_SZ*256;  // grouped layout [s>>3][256][8]

    bf16x8 qf[2][8];
    #pragma unroll
    for (int qt = 0; qt < 2; ++qt)
      #pragma unroll
      for (int ks = 0; ks < 8; ++ks)
        qf[qt][ks] = *(const bf16x8*)(Qbase + (size_t)(qrow0 + qt*16 + lr)*256 + ks*32 + lg*8);

    f32x4 zero4 = {0.f,0.f,0.f,0.f};
    f32x4 acc[2][16];
    #pragma unroll
    for (int qt=0;qt<2;++qt)
      #pragma unroll
      for (int dt=0;dt<16;++dt) acc[qt][dt] = zero4;
    float m[2][4], ls[2][4];
    #pragma unroll
    for (int qt=0;qt<2;++qt)
      #pragma unroll
      for (int r=0;r<4;++r){ m[qt][r] = -1e30f; ls[qt][r] = 0.f; }

    int kv0 = split*1024;
    char* Pw = Plds + w*2560;                     // [32 rows][stride 72B]

    // ---- prologue: stage K chunk 0 into buf 0
    #pragma unroll
    for (int i = 0; i < 4; ++i){
        int o = i*4096 + tid*16;
        int r = o >> 9, cb = o & 511;
        async16((const char*)Kbase + (size_t)(kv0 + r)*512 + (cb ^ ((r&7)<<4)), lds + o);
    }
    __syncthreads();

    int buf = 0;
    for (int ch = 0; ch < NCH; ++ch){
        int kvbase = kv0 + ch*CH_ROWS;
        // ---- prefetch next K chunk into buf^1 (overlaps with compute below)
        if (ch < NCH-1){
            int kvn = kvbase + CH_ROWS;
            char* Kn = lds + (buf^1)*16384;
            #pragma unroll
            for (int i = 0; i < 4; ++i){
                int o = i*4096 + tid*16;
                int r = o >> 9, cb = o & 511;
                async16((const char*)Kbase + (size_t)(kvn + r)*512 + (cb ^ ((r&7)<<4)), Kn + o);
            }
        }
        char* Kl = lds + buf*16384;

        // ---- QK^T: sc[qt][kt] = Q(32 rows) x K^T(32 cols), k-depth 256
        f32x4 sc[2][2];
        #pragma unroll
        for (int qt=0;qt<2;++qt){ sc[qt][0] = zero4; sc[qt][1] = zero4; }
        __builtin_amdgcn_s_setprio(1);
        #pragma unroll
        for (int ks=0;ks<8;++ks){
            #pragma unroll
            for (int kt=0;kt<2;++kt){
                int krow = kt*16 + lr;
                bf16x8 kf = *(const bf16x8*)(Kl + krow*512 + ((ks*64 + lg*16) ^ ((krow&7)<<4)));
                sc[0][kt] = MFMA16(qf[0][ks], kf, sc[0][kt]);
                sc[1][kt] = MFMA16(qf[1][ks], kf, sc[1][kt]);
            }
        }
        __builtin_amdgcn_s_setprio(0);

        // ---- online softmax (exp2 domain; defer-max THR=8, lane-local check)
        int need = 0;
        float lmax[2][4];
        #pragma unroll
        for (int qt=0;qt<2;++qt){
            #pragma unroll
            for (int r=0;r<4;++r){
                lmax[qt][r] = fmaxf(sc[qt][0][r], sc[qt][1][r]);
                need |= (lmax[qt][r] > m[qt][r] + 8.0f) ? 1 : 0;
            }
        }
        if (__any(need)){
            // rare path: full cross-lane max reduce + rescale
            #pragma unroll
            for (int qt=0;qt<2;++qt){
                #pragma unroll
                for (int r=0;r<4;++r){
                    float v = lmax[qt][r];
                    v = fmaxf(v, __shfl_xor(v, 1));
                    v = fmaxf(v, __shfl_xor(v, 2));
                    v = fmaxf(v, __shfl_xor(v, 4));
                    v = fmaxf(v, __shfl_xor(v, 8));
                    float mn = fmaxf(m[qt][r], v);
                    float alpha = __builtin_amdgcn_exp2f(m[qt][r] - mn);
                    m[qt][r] = mn;
                    ls[qt][r] *= alpha;
                    #pragma unroll
                    for (int dt=0;dt<16;++dt) acc[qt][dt][r] *= alpha;
                }
            }
        }
        #pragma unroll
        for (int qt=0;qt<2;++qt){
            #pragma unroll
            for (int r=0;r<4;++r){
                float mm = m[qt][r];
                int q = qt*16 + lg*4 + r;
                float p0 = __builtin_amdgcn_exp2f(sc[qt][0][r] - mm);
                float p1 = __builtin_amdgcn_exp2f(sc[qt][1][r] - mm);
                ls[qt][r] += p0 + p1;
                *(u16*)(Pw + q*P_STRIDE + lr*2)      = f2bf(p0);
                *(u16*)(Pw + q*P_STRIDE + 32 + lr*2) = f2bf(p1);
            }
        }

        // ---- PV: acc[qt][dt] += P(32 x 32) x V(32 x 256); V direct from L2
        bf16x8 pa[2];
        #pragma unroll
        for (int qt=0;qt<2;++qt)
            pa[qt] = *(const bf16x8*)(Pw + (qt*16 + lr)*P_STRIDE + lg*16);
        const u16* Vchunk = Vbase + (size_t)(kvbase/8 + lg)*2048;
        __builtin_amdgcn_s_setprio(1);
        #pragma unroll
        for (int dt=0;dt<16;++dt){
            bf16x8 vf = *(const bf16x8*)(Vchunk + (dt*16 + lr)*8);
            acc[0][dt] = MFMA16(pa[0], vf, acc[0][dt]);
            acc[1][dt] = MFMA16(pa[1], vf, acc[1][dt]);
        }
        __builtin_amdgcn_s_setprio(0);

        __syncthreads();   // drains K prefetch + all waves done with K buf before overwrite
        buf ^= 1;
    }

    // ---- final cross-lane sum reduce (once per kernel)
    float l[2][4];
    #pragma unroll
    for (int qt=0;qt<2;++qt){
        #pragma unroll
        for (int r=0;r<4;++r){
            float v = ls[qt][r];
            v += __shfl_xor(v, 1);
            v += __shfl_xor(v, 2);
            v += __shfl_xor(v, 4);
            v += __shfl_xor(v, 8);
            l[qt][r] = v;
        }
    }

    // ---- write partials
    size_t pbase = (size_t)(split*4 + bb)*S_SZ*256;
    #pragma unroll
    for (int qt=0;qt<2;++qt){
        #pragma unroll
        for (int dt=0;dt<16;++dt){
            #pragma unroll
            for (int r=0;r<4;++r){
                int row = qrow0 + qt*16 + lg*4 + r;
                Opart[pbase + (size_t)row*256 + dt*16 + lr] = acc[qt][dt][r];
            }
        }
    }
    if (lr == 0){
        #pragma unroll
        for (int qt=0;qt<2;++qt){
            #pragma unroll
            for (int r=0;r<4;++r){
                int row = qrow0 + qt*16 + lg*4 + r;
                Mpart[(split*4+bb)*S_SZ + row] = m[qt][r];
                Lpart[(split*4+bb)*S_SZ + row] = l[qt][r];
            }
        }
    }
}

// ---------------- combine kv-split partials -------------------------------------------------
__global__ void combine_kernel(const float* __restrict__ Opart, const float* __restrict__ Mpart,
                               const float* __restrict__ Lpart, float* __restrict__ out){
    int idx = blockIdx.x*256 + threadIdx.x;       // one float4 per thread
    int d4 = (idx & 63)*4;
    int row = idx >> 6;                            // b*4096 + s
    int bb = row >> 12, srow = row & 4095;
    float m[4], lv[4];
    #pragma unroll
    for (int i=0;i<4;++i){
        m[i]  = Mpart[(i*4+bb)*S_SZ + srow];
        lv[i] = Lpart[(i*4+bb)*S_SZ + srow];
    }
    float M = fmaxf(fmaxf(m[0],m[1]), fmaxf(m[2],m[3]));
    float L = 0.f; float wt[4];
    #pragma unroll
    for (int i=0;i<4;++i){ wt[i] = __builtin_amdgcn_exp2f(m[i]-M); L += lv[i]*wt[i]; }
    float inv = 1.f/L;
    float ox=0.f, oy=0.f, oz=0.f, ow=0.f;
    #pragma unroll
    for (int i=0;i<4;++i){
        float4 oi = *(const float4*)(Opart + (size_t)(i*4+bb)*S_SZ*256 + (size_t)srow*256 + d4);
        ox += oi.x*wt[i]; oy += oi.y*wt[i]; oz += oi.z*wt[i]; ow += oi.w*wt[i];
    }
    float4 o; o.x = ox*inv; o.y = oy*inv; o.z = oz*inv; o.w = ow*inv;
    *(float4*)(out + (size_t)row*256 + d4) = o;
}

extern "C" void kernel_launch(void* const* d_in, const int* in_sizes, int n_in,
                              void* d_out, int out_size, void* d_ws, size_t ws_size,
                              hipStream_t stream) {
    const float* q_in = (const float*)d_in[0];
    const float* k_in = (const float*)d_in[1];
    const float* v_in = (const float*)d_in[2];
    const float* Wq   = (const float*)d_in[3];
    const float* bq   = (const float*)d_in[4];
    const float* Wk   = (const float*)d_in[5];
    const float* bk   = (const float*)d_in[6];
    const float* Wv   = (const float*)d_in[7];
    const float* bv   = (const float*)d_in[8];

    char* ws = (char*)d_ws;
    u16*  Qb    = (u16*)ws;                         // 8,388,608 B
    u16*  Kb    = (u16*)(ws + 8388608);             // 8,388,608 B
    u16*  Vt    = (u16*)(ws + 16777216);            // 8,388,608 B
    u16*  Wt    = (u16*)(ws + 25165824);            // 393,216 B
    float* Opart = (float*)(ws + 33554432);         // 67,108,864 B
    float* Mpart = (float*)(ws + 100663296);        // 262,144 B
    float* Lpart = (float*)(ws + 100925440);        // 262,144 B
    float* out   = (float*)d_out;

    hipLaunchKernelGGL(wconv_kernel,   dim3(768),  dim3(256), 0, stream, Wq, Wk, Wv, Wt);
    hipLaunchKernelGGL(proj_kernel,    dim3(256),  dim3(256), 0, stream, q_in, Wt,        bq, Qb, SCL, 0);
    hipLaunchKernelGGL(proj_kernel,    dim3(256),  dim3(256), 0, stream, k_in, Wt+65536,  bk, Kb, 1.f, 0);
    hipLaunchKernelGGL(proj_kernel,    dim3(256),  dim3(256), 0, stream, v_in, Wt+131072, bv, Vt, 1.f, 1);
    hipLaunchKernelGGL(attn_kernel,    dim3(512),  dim3(256), 0, stream, Qb, Kb, Vt, Opart, Mpart, Lpart);
    hipLaunchKernelGGL(combine_kernel, dim3(4096), dim3(256), 0, stream, Opart, Mpart, Lpart, out);
}

// Round 6
// 218.362 us; speedup vs baseline: 1.5625x; 1.5625x over previous
//
#include <hip/hip_runtime.h>
#include <hip/hip_bf16.h>
#include <stdint.h>

#define S_SZ 4096
// (1/sqrt(256)) * log2(e): scores come out in exp2 domain
#define SCL 0.09016844005586937f

typedef short bf16x8 __attribute__((ext_vector_type(8)));
typedef float f32x4 __attribute__((ext_vector_type(4)));
typedef unsigned short u16;

#define MFMA16(a,b,c) __builtin_amdgcn_mfma_f32_16x16x32_bf16(a,b,c,0,0,0)

__device__ __forceinline__ u16 f2bf(float f){
    union { float f; uint32_t u; } v; v.f = f;
    return (u16)((v.u + 0x7FFFu + ((v.u >> 16) & 1u)) >> 16);
}

__device__ __forceinline__ void async16(const void* g, void* l){
    __builtin_amdgcn_global_load_lds(
        (const __attribute__((address_space(1))) unsigned int*)g,
        (__attribute__((address_space(3))) unsigned int*)l, 16, 0, 0);
}

// ---------------- weight transpose + cast: Wt[p][dout][din] = bf16(W[din][dout]) -----------
__global__ void wconv_kernel(const float* __restrict__ Wq, const float* __restrict__ Wk,
                             const float* __restrict__ Wv, u16* __restrict__ Wt){
    int idx = blockIdx.x*256 + threadIdx.x;       // 0..196607
    int p = idx >> 16; int rem = idx & 65535;
    int dout = rem >> 8, din = rem & 255;
    const float* W = (p==0) ? Wq : ((p==1) ? Wk : Wv);
    Wt[idx] = f2bf(W[din*256 + dout]);
}

// ---------------- projection GEMM: Out = bf16((X @ W + b) * scale) --------------------------
// mode 0: row-major [row][256]   mode 1: V grouped-transposed [b][s>>3][256][s&7]
__global__ void proj_kernel(const float* __restrict__ X, const u16* __restrict__ Wt,
                            const float* __restrict__ bias, u16* __restrict__ Out,
                            float scale, int mode){
    int w = threadIdx.x >> 6, lane = threadIdx.x & 63;
    int lr = lane & 15, lg = lane >> 4;
    int r0 = blockIdx.x * 64 + w * 16;            // this wave's 16 rows

    bf16x8 a[8];
    #pragma unroll
    for (int ks = 0; ks < 8; ++ks){
        const float* src = X + (size_t)(r0 + lr)*256 + ks*32 + lg*8;
        float4 f0 = *(const float4*)src;
        float4 f1 = *(const float4*)(src+4);
        bf16x8 t;
        t[0]=f2bf(f0.x); t[1]=f2bf(f0.y); t[2]=f2bf(f0.z); t[3]=f2bf(f0.w);
        t[4]=f2bf(f1.x); t[5]=f2bf(f1.y); t[6]=f2bf(f1.z); t[7]=f2bf(f1.w);
        a[ks]=t;
    }
    #pragma unroll
    for (int dt = 0; dt < 16; ++dt){
        f32x4 acc = {0.f,0.f,0.f,0.f};
        #pragma unroll
        for (int ks = 0; ks < 8; ++ks){
            bf16x8 b = *(const bf16x8*)(Wt + (size_t)(dt*16 + lr)*256 + ks*32 + lg*8);
            acc = MFMA16(a[ks], b, acc);
        }
        float bv = bias[dt*16 + lr];
        if (mode == 0){
            #pragma unroll
            for (int r = 0; r < 4; ++r){
                int row = r0 + lg*4 + r;
                Out[(size_t)row*256 + dt*16 + lr] = f2bf((acc[r] + bv)*scale);
            }
        } else {
            int row = r0 + lg*4;                  // 4 consecutive s rows
            int bb = row >> 12;
            int s  = row & 4095;
            ushort4 pk;
            pk.x = f2bf(acc[0]+bv); pk.y = f2bf(acc[1]+bv);
            pk.z = f2bf(acc[2]+bv); pk.w = f2bf(acc[3]+bv);
            u16* dst = Out + (size_t)bb*1048576 + (size_t)(s>>3)*2048 + (dt*16+lr)*8 + (s&7);
            *(ushort4*)dst = pk;
        }
    }
}

// ---------------- flash attention, kv-split partials ---------------------------------------
// grid 512 (XCD-aware), block 512 thr = 8 waves x 16 q rows (128 q rows/block)
// Q frags in regs; K,V chunk 32 double-buffered in LDS; P per-wave in LDS.
// Softmax: per-lane running sum; cross-lane max reduce only on rare (> m+8) trigger.
#define CH_ROWS 32
#define NCH     32          /* 1024 kv rows per split / 32 */
#define P_STRIDE 72

__global__ __launch_bounds__(512, 4)
void attn_kernel(const u16* __restrict__ Qb, const u16* __restrict__ Kb,
                 const u16* __restrict__ Vt, float* __restrict__ Opart,
                 float* __restrict__ Mpart, float* __restrict__ Lpart){
    __shared__ char lds[74752];   // K0@0 K1@16384 V0@32768 V1@49152 P@65536 (8x1152)
    int tid = threadIdx.x;
    int w = tid >> 6, lane = tid & 63;
    int lr = lane & 15, lg = lane >> 4;

    // XCD-aware decode: same (bb,split) combo stays on one XCD for L2 reuse
    int bid = blockIdx.x;
    int xcd = bid & 7;
    int loc = bid >> 3;                 // 0..63
    int combo = xcd*2 + (loc >> 5);     // 0..15
    int qb = loc & 31;
    int bb = combo >> 2;
    int split = combo & 3;
    int qrow0 = qb*128 + w*16;

    const u16* Qbase = Qb + (size_t)bb*S_SZ*256;
    const u16* Kbase = Kb + (size_t)bb*S_SZ*256;
    const u16* Vbase = Vt + (size_t)bb*S_SZ*256;  // grouped layout [s>>3][256][8]

    bf16x8 qf[8];
    #pragma unroll
    for (int ks = 0; ks < 8; ++ks)
        qf[ks] = *(const bf16x8*)(Qbase + (size_t)(qrow0 + lr)*256 + ks*32 + lg*8);

    f32x4 zero4 = {0.f,0.f,0.f,0.f};
    f32x4 acc[16];
    #pragma unroll
    for (int dt=0;dt<16;++dt) acc[dt] = zero4;
    float m[4], ls[4];
    #pragma unroll
    for (int r=0;r<4;++r){ m[r] = -1e30f; ls[r] = 0.f; }

    int kv0 = split*1024;
    char* Pw = lds + 65536 + w*1152;              // [16 rows][stride 72B]

    // ---- prologue: stage K,V chunk 0 into buf 0 (2 async16 each, 512 threads)
    #pragma unroll
    for (int i = 0; i < 2; ++i){
        int o = i*8192 + tid*16;
        int r = o >> 9, cb = o & 511;
        async16((const char*)Kbase + (size_t)(kv0 + r)*512 + (cb ^ ((r&7)<<4)), lds + o);
    }
    const char* vsrc0 = (const char*)Vbase + (size_t)kv0*512;
    #pragma unroll
    for (int i = 0; i < 2; ++i){
        int o = i*8192 + tid*16;
        async16(vsrc0 + o, lds + 32768 + o);
    }
    __syncthreads();

    int buf = 0;
    for (int ch = 0; ch < NCH; ++ch){
        // ---- prefetch next chunk into buf^1 (overlaps with compute below)
        if (ch < NCH-1){
            int kvn = kv0 + (ch+1)*CH_ROWS;
            char* Kn = lds + (buf^1)*16384;
            char* Vn = lds + 32768 + (buf^1)*16384;
            #pragma unroll
            for (int i = 0; i < 2; ++i){
                int o = i*8192 + tid*16;
                int r = o >> 9, cb = o & 511;
                async16((const char*)Kbase + (size_t)(kvn + r)*512 + (cb ^ ((r&7)<<4)), Kn + o);
            }
            const char* vsrc = (const char*)Vbase + (size_t)kvn*512;
            #pragma unroll
            for (int i = 0; i < 2; ++i){
                int o = i*8192 + tid*16;
                async16(vsrc + o, Vn + o);
            }
        }
        char* Kl = lds + buf*16384;
        char* Vl = lds + 32768 + buf*16384;

        // ---- QK^T: sc[kt] = Q(16 rows) x K^T(32 cols), k-depth 256
        f32x4 sc[2];
        sc[0] = zero4; sc[1] = zero4;
        __builtin_amdgcn_s_setprio(1);
        #pragma unroll
        for (int ks=0;ks<8;++ks){
            #pragma unroll
            for (int kt=0;kt<2;++kt){
                int krow = kt*16 + lr;
                bf16x8 kf = *(const bf16x8*)(Kl + krow*512 + ((ks*64 + lg*16) ^ ((krow&7)<<4)));
                sc[kt] = MFMA16(qf[ks], kf, sc[kt]);
            }
        }
        __builtin_amdgcn_s_setprio(0);

        // ---- online softmax (exp2 domain; defer-max THR=8, lane-local check)
        int need = 0;
        float lmax[4];
        #pragma unroll
        for (int r=0;r<4;++r){
            lmax[r] = fmaxf(sc[0][r], sc[1][r]);
            need |= (lmax[r] > m[r] + 8.0f) ? 1 : 0;
        }
        if (__any(need)){
            // rare path: full cross-lane max reduce + rescale
            #pragma unroll
            for (int r=0;r<4;++r){
                float v = lmax[r];
                v = fmaxf(v, __shfl_xor(v, 1));
                v = fmaxf(v, __shfl_xor(v, 2));
                v = fmaxf(v, __shfl_xor(v, 4));
                v = fmaxf(v, __shfl_xor(v, 8));
                float mn = fmaxf(m[r], v);
                float alpha = __builtin_amdgcn_exp2f(m[r] - mn);
                m[r] = mn;
                ls[r] *= alpha;
                #pragma unroll
                for (int dt=0;dt<16;++dt) acc[dt][r] *= alpha;
            }
        }
        #pragma unroll
        for (int r=0;r<4;++r){
            float mm = m[r];
            int q = lg*4 + r;
            float p0 = __builtin_amdgcn_exp2f(sc[0][r] - mm);
            float p1 = __builtin_amdgcn_exp2f(sc[1][r] - mm);
            ls[r] += p0 + p1;
            *(u16*)(Pw + q*P_STRIDE + lr*2)      = f2bf(p0);
            *(u16*)(Pw + q*P_STRIDE + 32 + lr*2) = f2bf(p1);
        }

        // ---- PV: acc[dt] += P(16 x 32) x V(32 x 256)
        bf16x8 pa = *(const bf16x8*)(Pw + lr*P_STRIDE + lg*16);
        __builtin_amdgcn_s_setprio(1);
        #pragma unroll
        for (int dt=0;dt<16;++dt){
            bf16x8 vf = *(const bf16x8*)(Vl + lg*4096 + (dt*16 + lr)*16);
            acc[dt] = MFMA16(pa, vf, acc[dt]);
        }
        __builtin_amdgcn_s_setprio(0);

        __syncthreads();   // drains prefetch vmcnt + all waves done with buf before overwrite
        buf ^= 1;
    }

    // ---- final cross-lane sum reduce (once per kernel)
    float l[4];
    #pragma unroll
    for (int r=0;r<4;++r){
        float v = ls[r];
        v += __shfl_xor(v, 1);
        v += __shfl_xor(v, 2);
        v += __shfl_xor(v, 4);
        v += __shfl_xor(v, 8);
        l[r] = v;
    }

    // ---- write partials
    size_t pbase = (size_t)(split*4 + bb)*S_SZ*256;
    #pragma unroll
    for (int dt=0;dt<16;++dt){
        #pragma unroll
        for (int r=0;r<4;++r){
            int row = qrow0 + lg*4 + r;
            Opart[pbase + (size_t)row*256 + dt*16 + lr] = acc[dt][r];
        }
    }
    if (lr == 0){
        #pragma unroll
        for (int r=0;r<4;++r){
            int row = qrow0 + lg*4 + r;
            Mpart[(split*4+bb)*S_SZ + row] = m[r];
            Lpart[(split*4+bb)*S_SZ + row] = l[r];
        }
    }
}

// ---------------- combine kv-split partials -------------------------------------------------
__global__ void combine_kernel(const float* __restrict__ Opart, const float* __restrict__ Mpart,
                               const float* __restrict__ Lpart, float* __restrict__ out){
    int idx = blockIdx.x*256 + threadIdx.x;       // one float4 per thread
    int d4 = (idx & 63)*4;
    int row = idx >> 6;                            // b*4096 + s
    int bb = row >> 12, srow = row & 4095;
    float m[4], lv[4];
    #pragma unroll
    for (int i=0;i<4;++i){
        m[i]  = Mpart[(i*4+bb)*S_SZ + srow];
        lv[i] = Lpart[(i*4+bb)*S_SZ + srow];
    }
    float M = fmaxf(fmaxf(m[0],m[1]), fmaxf(m[2],m[3]));
    float L = 0.f; float wt[4];
    #pragma unroll
    for (int i=0;i<4;++i){ wt[i] = __builtin_amdgcn_exp2f(m[i]-M); L += lv[i]*wt[i]; }
    float inv = 1.f/L;
    float ox=0.f, oy=0.f, oz=0.f, ow=0.f;
    #pragma unroll
    for (int i=0;i<4;++i){
        float4 oi = *(const float4*)(Opart + (size_t)(i*4+bb)*S_SZ*256 + (size_t)srow*256 + d4);
        ox += oi.x*wt[i]; oy += oi.y*wt[i]; oz += oi.z*wt[i]; ow += oi.w*wt[i];
    }
    float4 o; o.x = ox*inv; o.y = oy*inv; o.z = oz*inv; o.w = ow*inv;
    *(float4*)(out + (size_t)row*256 + d4) = o;
}

extern "C" void kernel_launch(void* const* d_in, const int* in_sizes, int n_in,
                              void* d_out, int out_size, void* d_ws, size_t ws_size,
                              hipStream_t stream) {
    const float* q_in = (const float*)d_in[0];
    const float* k_in = (const float*)d_in[1];
    const float* v_in = (const float*)d_in[2];
    const float* Wq   = (const float*)d_in[3];
    const float* bq   = (const float*)d_in[4];
    const float* Wk   = (const float*)d_in[5];
    const float* bk   = (const float*)d_in[6];
    const float* Wv   = (const float*)d_in[7];
    const float* bv   = (const float*)d_in[8];

    char* ws = (char*)d_ws;
    u16*  Qb    = (u16*)ws;                         // 8,388,608 B
    u16*  Kb    = (u16*)(ws + 8388608);             // 8,388,608 B
    u16*  Vt    = (u16*)(ws + 16777216);            // 8,388,608 B
    u16*  Wt    = (u16*)(ws + 25165824);            // 393,216 B
    float* Opart = (float*)(ws + 33554432);         // 67,108,864 B
    float* Mpart = (float*)(ws + 100663296);        // 262,144 B
    float* Lpart = (float*)(ws + 100925440);        // 262,144 B
    float* out   = (float*)d_out;

    hipLaunchKernelGGL(wconv_kernel,   dim3(768),  dim3(256), 0, stream, Wq, Wk, Wv, Wt);
    hipLaunchKernelGGL(proj_kernel,    dim3(256),  dim3(256), 0, stream, q_in, Wt,        bq, Qb, SCL, 0);
    hipLaunchKernelGGL(proj_kernel,    dim3(256),  dim3(256), 0, stream, k_in, Wt+65536,  bk, Kb, 1.f, 0);
    hipLaunchKernelGGL(proj_kernel,    dim3(256),  dim3(256), 0, stream, v_in, Wt+131072, bv, Vt, 1.f, 1);
    hipLaunchKernelGGL(attn_kernel,    dim3(512),  dim3(512), 0, stream, Qb, Kb, Vt, Opart, Mpart, Lpart);
    hipLaunchKernelGGL(combine_kernel, dim3(4096), dim3(256), 0, stream, Opart, Mpart, Lpart, out);
}

// Round 7
// 192.175 us; speedup vs baseline: 1.7754x; 1.1363x over previous
//
#include <hip/hip_runtime.h>
#include <hip/hip_bf16.h>
#include <stdint.h>

#define S_SZ 4096
// (1/sqrt(256)) * log2(e): scores come out in exp2 domain
#define SCL 0.09016844005586937f

typedef short bf16x8 __attribute__((ext_vector_type(8)));
typedef float f32x4 __attribute__((ext_vector_type(4)));
typedef float f32x16 __attribute__((ext_vector_type(16)));
typedef unsigned short u16;
typedef unsigned int u32;

#define MFMA16(a,b,c) __builtin_amdgcn_mfma_f32_16x16x32_bf16(a,b,c,0,0,0)
#define MFMA32(a,b,c) __builtin_amdgcn_mfma_f32_32x32x16_bf16(a,b,c,0,0,0)

__device__ __forceinline__ u16 f2bf(float f){
    union { float f; uint32_t u; } v; v.f = f;
    return (u16)((v.u + 0x7FFFu + ((v.u >> 16) & 1u)) >> 16);
}
__device__ __forceinline__ u32 pk2(float a, float b){
    return (u32)f2bf(a) | ((u32)f2bf(b) << 16);
}

__device__ __forceinline__ void async16(const void* g, void* l){
    __builtin_amdgcn_global_load_lds(
        (const __attribute__((address_space(1))) unsigned int*)g,
        (__attribute__((address_space(3))) unsigned int*)l, 16, 0, 0);
}

// ---------------- weight transpose + cast: Wt[p][dout][din] = bf16(W[din][dout]) -----------
__global__ void wconv_kernel(const float* __restrict__ Wq, const float* __restrict__ Wk,
                             const float* __restrict__ Wv, u16* __restrict__ Wt){
    int idx = blockIdx.x*256 + threadIdx.x;       // 0..196607
    int p = idx >> 16; int rem = idx & 65535;
    int dout = rem >> 8, din = rem & 255;
    const float* W = (p==0) ? Wq : ((p==1) ? Wk : Wv);
    Wt[idx] = f2bf(W[din*256 + dout]);
}

// ---------------- projection GEMM: Out = bf16((X @ W + b) * scale) --------------------------
// mode 0: row-major [row][256]
// mode 1: V grouped      [b][s>>3][256][s&7]   (V^T A-frags read 16B-linear)
// mode 2: K d-grouped    [b][d>>3][s(4096)][d&7] (K A-frags read 16B-linear)
__global__ void proj_kernel(const float* __restrict__ X, const u16* __restrict__ Wt,
                            const float* __restrict__ bias, u16* __restrict__ Out,
                            float scale, int mode){
    int w = threadIdx.x >> 6, lane = threadIdx.x & 63;
    int lr = lane & 15, lg = lane >> 4;
    int r0 = blockIdx.x * 64 + w * 16;            // this wave's 16 rows

    bf16x8 a[8];
    #pragma unroll
    for (int ks = 0; ks < 8; ++ks){
        const float* src = X + (size_t)(r0 + lr)*256 + ks*32 + lg*8;
        float4 f0 = *(const float4*)src;
        float4 f1 = *(const float4*)(src+4);
        bf16x8 t;
        t[0]=f2bf(f0.x); t[1]=f2bf(f0.y); t[2]=f2bf(f0.z); t[3]=f2bf(f0.w);
        t[4]=f2bf(f1.x); t[5]=f2bf(f1.y); t[6]=f2bf(f1.z); t[7]=f2bf(f1.w);
        a[ks]=t;
    }
    #pragma unroll
    for (int dt = 0; dt < 16; ++dt){
        f32x4 acc = {0.f,0.f,0.f,0.f};
        #pragma unroll
        for (int ks = 0; ks < 8; ++ks){
            bf16x8 b = *(const bf16x8*)(Wt + (size_t)(dt*16 + lr)*256 + ks*32 + lg*8);
            acc = MFMA16(a[ks], b, acc);
        }
        float bv = bias[dt*16 + lr];
        int d = dt*16 + lr;
        if (mode == 0){
            #pragma unroll
            for (int r = 0; r < 4; ++r){
                int row = r0 + lg*4 + r;
                Out[(size_t)row*256 + d] = f2bf((acc[r] + bv)*scale);
            }
        } else if (mode == 1){
            int row = r0 + lg*4;                  // 4 consecutive s rows
            int bb = row >> 12;
            int s  = row & 4095;
            ushort4 pk;
            pk.x = f2bf(acc[0]+bv); pk.y = f2bf(acc[1]+bv);
            pk.z = f2bf(acc[2]+bv); pk.w = f2bf(acc[3]+bv);
            u16* dst = Out + (size_t)bb*1048576 + (size_t)(s>>3)*2048 + d*8 + (s&7);
            *(ushort4*)dst = pk;
        } else {
            int row = r0 + lg*4;
            int bb = row >> 12;
            int s  = row & 4095;
            u16* dst = Out + (size_t)bb*1048576 + (size_t)(d>>3)*32768 + (size_t)s*8 + (d&7);
            #pragma unroll
            for (int r = 0; r < 4; ++r)
                dst[r*8] = f2bf(acc[r]+bv);
        }
    }
}

// ---------------- flash attention, kv-split partials ---------------------------------------
// grid 512 (XCD-aware), block 256 = 4 waves x 32 q rows (128 q rows/block)
// Swapped-operand 32x32x16 MFMA: S^T = mfma(K,Q) -> lane owns q=lane&31 column;
// softmax lane-local; P^T packed in regs (shfl_xor 32); PV = mfma(V^T, P^T) = O^T.
// K,V chunk 32 double-buffered in LDS; all frag reads 16B-linear (conflict-free).
#define CH_ROWS 32
#define NCH     32          /* 1024 kv rows per split / 32 */

__global__ __launch_bounds__(256, 2)
void attn_kernel(const u16* __restrict__ Qb, const u16* __restrict__ Kb,
                 const u16* __restrict__ Vt, float* __restrict__ Opart,
                 float* __restrict__ Mpart, float* __restrict__ Lpart){
    __shared__ char lds[65536];   // K0@0 K1@16384 V0@32768 V1@49152
    int tid = threadIdx.x;
    int w = tid >> 6, lane = tid & 63;
    int q5 = lane & 31, hi = lane >> 5;

    // XCD-aware decode: same (bb,split) combo stays on one XCD for L2 reuse
    int bid = blockIdx.x;
    int xcd = bid & 7;
    int loc = bid >> 3;                 // 0..63
    int combo = xcd*2 + (loc >> 5);     // 0..15
    int qb = loc & 31;
    int bb = combo >> 2;
    int split = combo & 3;
    int qrow0 = qb*128 + w*32;

    const char* Qbyte = (const char*)Qb + (size_t)bb*2097152;
    const char* Kbyte = (const char*)Kb + (size_t)bb*2097152;  // [d>>3][s][d&7]
    const char* Vbyte = (const char*)Vt + (size_t)bb*2097152;  // [s>>3][256][s&7]

    // Q fragments (B operand): lane holds q=q5, depth d = c*16 + hi*8 + j
    bf16x8 qf[16];
    #pragma unroll
    for (int c = 0; c < 16; ++c)
        qf[c] = *(const bf16x8*)(Qbyte + (size_t)(qrow0 + q5)*512 + c*32 + hi*16);

    f32x16 acc[8];
    #pragma unroll
    for (int dt=0;dt<8;++dt)
        #pragma unroll
        for (int i=0;i<16;++i) acc[dt][i] = 0.f;
    float m = -1e30f, ls = 0.f;

    int kv0 = split*1024;

    // ---- prologue: stage K,V chunk 0 into buf 0
    #pragma unroll
    for (int i = 0; i < 4; ++i){
        int o = i*4096 + tid*16;
        async16(Kbyte + ((size_t)(o>>9)*65536 + (size_t)kv0*16 + (o&511)), lds + o);
    }
    #pragma unroll
    for (int i = 0; i < 4; ++i){
        int o = i*4096 + tid*16;
        async16(Vbyte + (size_t)kv0*512 + o, lds + 32768 + o);
    }
    __syncthreads();

    int buf = 0;
    for (int ch = 0; ch < NCH; ++ch){
        // ---- prefetch next chunk into buf^1 (overlaps with compute below)
        if (ch < NCH-1){
            int kvn = kv0 + (ch+1)*CH_ROWS;
            char* Kn = lds + (buf^1)*16384;
            char* Vn = lds + 32768 + (buf^1)*16384;
            #pragma unroll
            for (int i = 0; i < 4; ++i){
                int o = i*4096 + tid*16;
                async16(Kbyte + ((size_t)(o>>9)*65536 + (size_t)kvn*16 + (o&511)), Kn + o);
            }
            #pragma unroll
            for (int i = 0; i < 4; ++i){
                int o = i*4096 + tid*16;
                async16(Vbyte + (size_t)kvn*512 + o, Vn + o);
            }
        }
        char* Kl = lds + buf*16384;
        char* Vl = lds + 32768 + buf*16384;

        // ---- QK^T (swapped): sc = S^T[kv32][q32], depth 256 in 16 chunks
        f32x16 sc;
        #pragma unroll
        for (int i=0;i<16;++i) sc[i] = 0.f;
        __builtin_amdgcn_s_setprio(1);
        #pragma unroll
        for (int c = 0; c < 16; ++c){
            bf16x8 kf = *(const bf16x8*)(Kl + (2*c + hi)*512 + q5*16);
            sc = MFMA32(kf, qf[c], sc);
        }
        __builtin_amdgcn_s_setprio(0);

        // ---- softmax (exp2 domain; defer-max THR=8; all lane-local)
        float lmax = sc[0];
        #pragma unroll
        for (int i=1;i<16;++i) lmax = fmaxf(lmax, sc[i]);
        float pm = fmaxf(lmax, __shfl_xor(lmax, 32));
        if (__any(pm > m + 8.0f)){
            float mn = fmaxf(m, pm);
            float alpha = __builtin_amdgcn_exp2f(m - mn);
            m = mn;
            ls *= alpha;
            #pragma unroll
            for (int dt=0;dt<8;++dt) acc[dt] *= alpha;
        }
        float p[16];
        float rs = 0.f;
        #pragma unroll
        for (int i=0;i<16;++i){ p[i] = __builtin_amdgcn_exp2f(sc[i] - m); rs += p[i]; }
        ls += rs;

        // ---- pack P^T B-frags in registers (kv halves via shfl_xor 32)
        bf16x8 pf[2];
        #pragma unroll
        for (int h=0; h<2; ++h){
            const int o8 = h*8;
            u32 A0 = pk2(p[o8+0], p[o8+1]);
            u32 A1 = pk2(p[o8+2], p[o8+3]);
            u32 B0 = pk2(p[o8+4], p[o8+5]);
            u32 B1 = pk2(p[o8+6], p[o8+7]);
            u32 XA0 = __shfl_xor(A0, 32);
            u32 XA1 = __shfl_xor(A1, 32);
            u32 XB0 = __shfl_xor(B0, 32);
            u32 XB1 = __shfl_xor(B1, 32);
            union { u32 wd[4]; bf16x8 v; } u;
            u.wd[0] = hi ? XB0 : A0;
            u.wd[1] = hi ? XB1 : A1;
            u.wd[2] = hi ? B0  : XA0;
            u.wd[3] = hi ? B1  : XA1;
            pf[h] = u.v;
        }

        // ---- PV (swapped): acc[dt] = O^T tiles += mfma(V^T-frag, P^T-frag)
        __builtin_amdgcn_s_setprio(1);
        #pragma unroll
        for (int h=0; h<2; ++h){
            #pragma unroll
            for (int dt=0; dt<8; ++dt){
                bf16x8 vf = *(const bf16x8*)(Vl + (2*h + hi)*4096 + (dt*32 + q5)*16);
                acc[dt] = MFMA32(vf, pf[h], acc[dt]);
            }
        }
        __builtin_amdgcn_s_setprio(0);

        __syncthreads();   // drains prefetch vmcnt + all waves done with buf before overwrite
        buf ^= 1;
    }

    // ---- finalize l (pair sum), write partials
    float l = ls + __shfl_xor(ls, 32);

    size_t pbase = (size_t)(split*4 + bb)*S_SZ*256;
    float* orow = Opart + pbase + (size_t)(qrow0 + q5)*256;
    #pragma unroll
    for (int dt=0; dt<8; ++dt){
        #pragma unroll
        for (int g=0; g<4; ++g){
            int d0 = dt*32 + g*8 + hi*4;
            float4 v;
            v.x = acc[dt][4*g+0]; v.y = acc[dt][4*g+1];
            v.z = acc[dt][4*g+2]; v.w = acc[dt][4*g+3];
            *(float4*)(orow + d0) = v;
        }
    }
    if (lane < 32){
        int row = qrow0 + q5;
        Mpart[(split*4+bb)*S_SZ + row] = m;
        Lpart[(split*4+bb)*S_SZ + row] = l;
    }
}

// ---------------- combine kv-split partials -------------------------------------------------
__global__ void combine_kernel(const float* __restrict__ Opart, const float* __restrict__ Mpart,
                               const float* __restrict__ Lpart, float* __restrict__ out){
    int idx = blockIdx.x*256 + threadIdx.x;       // one float4 per thread
    int d4 = (idx & 63)*4;
    int row = idx >> 6;                            // b*4096 + s
    int bb = row >> 12, srow = row & 4095;
    float m[4], lv[4];
    #pragma unroll
    for (int i=0;i<4;++i){
        m[i]  = Mpart[(i*4+bb)*S_SZ + srow];
        lv[i] = Lpart[(i*4+bb)*S_SZ + srow];
    }
    float M = fmaxf(fmaxf(m[0],m[1]), fmaxf(m[2],m[3]));
    float L = 0.f; float wt[4];
    #pragma unroll
    for (int i=0;i<4;++i){ wt[i] = __builtin_amdgcn_exp2f(m[i]-M); L += lv[i]*wt[i]; }
    float inv = 1.f/L;
    float ox=0.f, oy=0.f, oz=0.f, ow=0.f;
    #pragma unroll
    for (int i=0;i<4;++i){
        float4 oi = *(const float4*)(Opart + (size_t)(i*4+bb)*S_SZ*256 + (size_t)srow*256 + d4);
        ox += oi.x*wt[i]; oy += oi.y*wt[i]; oz += oi.z*wt[i]; ow += oi.w*wt[i];
    }
    float4 o; o.x = ox*inv; o.y = oy*inv; o.z = oz*inv; o.w = ow*inv;
    *(float4*)(out + (size_t)row*256 + d4) = o;
}

extern "C" void kernel_launch(void* const* d_in, const int* in_sizes, int n_in,
                              void* d_out, int out_size, void* d_ws, size_t ws_size,
                              hipStream_t stream) {
    const float* q_in = (const float*)d_in[0];
    const float* k_in = (const float*)d_in[1];
    const float* v_in = (const float*)d_in[2];
    const float* Wq   = (const float*)d_in[3];
    const float* bq   = (const float*)d_in[4];
    const float* Wk   = (const float*)d_in[5];
    const float* bk   = (const float*)d_in[6];
    const float* Wv   = (const float*)d_in[7];
    const float* bv   = (const float*)d_in[8];

    char* ws = (char*)d_ws;
    u16*  Qb    = (u16*)ws;                         // 8,388,608 B
    u16*  Kb    = (u16*)(ws + 8388608);             // 8,388,608 B
    u16*  Vt    = (u16*)(ws + 16777216);            // 8,388,608 B
    u16*  Wt    = (u16*)(ws + 25165824);            // 393,216 B
    float* Opart = (float*)(ws + 33554432);         // 67,108,864 B
    float* Mpart = (float*)(ws + 100663296);        // 262,144 B
    float* Lpart = (float*)(ws + 100925440);        // 262,144 B
    float* out   = (float*)d_out;

    hipLaunchKernelGGL(wconv_kernel,   dim3(768),  dim3(256), 0, stream, Wq, Wk, Wv, Wt);
    hipLaunchKernelGGL(proj_kernel,    dim3(256),  dim3(256), 0, stream, q_in, Wt,        bq, Qb, SCL, 0);
    hipLaunchKernelGGL(proj_kernel,    dim3(256),  dim3(256), 0, stream, k_in, Wt+65536,  bk, Kb, 1.f, 2);
    hipLaunchKernelGGL(proj_kernel,    dim3(256),  dim3(256), 0, stream, v_in, Wt+131072, bv, Vt, 1.f, 1);
    hipLaunchKernelGGL(attn_kernel,    dim3(512),  dim3(256), 0, stream, Qb, Kb, Vt, Opart, Mpart, Lpart);
    hipLaunchKernelGGL(combine_kernel, dim3(4096), dim3(256), 0, stream, Opart, Mpart, Lpart, out);
}

// Round 8
// 152.243 us; speedup vs baseline: 2.2411x; 1.2623x over previous
//
#include <hip/hip_runtime.h>
#include <hip/hip_bf16.h>
#include <stdint.h>

#define S_SZ 4096
// (1/sqrt(256)) * log2(e): scores come out in exp2 domain
#define SCL 0.09016844005586937f

typedef short bf16x8 __attribute__((ext_vector_type(8)));
typedef float f32x4 __attribute__((ext_vector_type(4)));
typedef float f32x16 __attribute__((ext_vector_type(16)));
typedef unsigned short u16;
typedef unsigned int u32;

#define MFMA16(a,b,c) __builtin_amdgcn_mfma_f32_16x16x32_bf16(a,b,c,0,0,0)
#define MFMA32(a,b,c) __builtin_amdgcn_mfma_f32_32x32x16_bf16(a,b,c,0,0,0)

// HW packed f32->bf16 (RNE): dst = bf(lo) | bf(hi)<<16
__device__ __forceinline__ u32 cvtpk(float lo, float hi){
    u32 r;
    asm("v_cvt_pk_bf16_f32 %0, %1, %2" : "=v"(r) : "v"(lo), "v"(hi));
    return r;
}
__device__ __forceinline__ u16 cvt1(float a){ return (u16)cvtpk(a, a); }

__device__ __forceinline__ void async16(const void* g, void* l){
    __builtin_amdgcn_global_load_lds(
        (const __attribute__((address_space(1))) unsigned int*)g,
        (__attribute__((address_space(3))) unsigned int*)l, 16, 0, 0);
}

// ---------------- weight transpose + cast: Wt[p][dout][din] = bf16(W[din][dout]) -----------
__global__ void wconv_kernel(const float* __restrict__ Wq, const float* __restrict__ Wk,
                             const float* __restrict__ Wv, u16* __restrict__ Wt){
    int idx = blockIdx.x*256 + threadIdx.x;       // 0..196607
    int p = idx >> 16; int rem = idx & 65535;
    int dout = rem >> 8, din = rem & 255;
    const float* W = (p==0) ? Wq : ((p==1) ? Wk : Wv);
    Wt[idx] = cvt1(W[din*256 + dout]);
}

// ---------------- fused projections: one kernel, 3 slabs of 256 blocks ----------------------
// p=0: Q row-major [row][256], scaled
// p=1: K d-grouped [b][d>>3][s(4096)][d&7]
// p=2: V grouped   [b][s>>3][256][s&7]
__global__ void proj_all_kernel(const float* __restrict__ Xq, const float* __restrict__ Xk,
                                const float* __restrict__ Xv, const u16* __restrict__ Wt,
                                const float* __restrict__ bq, const float* __restrict__ bk,
                                const float* __restrict__ bv,
                                u16* __restrict__ Qb, u16* __restrict__ Kb, u16* __restrict__ Vt){
    int bid = blockIdx.x;
    int p = bid >> 8;
    const float* X    = (p==0) ? Xq : ((p==1) ? Xk : Xv);
    const float* bias = (p==0) ? bq : ((p==1) ? bk : bv);
    u16* Out          = (p==0) ? Qb : ((p==1) ? Kb : Vt);
    const u16* Wp     = Wt + p*65536;
    float scale = (p==0) ? SCL : 1.f;

    int w = threadIdx.x >> 6, lane = threadIdx.x & 63;
    int lr = lane & 15, lg = lane >> 4;
    int r0 = (bid & 255) * 64 + w * 16;           // this wave's 16 rows

    bf16x8 a[8];
    #pragma unroll
    for (int ks = 0; ks < 8; ++ks){
        const float* src = X + (size_t)(r0 + lr)*256 + ks*32 + lg*8;
        float4 f0 = *(const float4*)src;
        float4 f1 = *(const float4*)(src+4);
        union { u32 wd[4]; bf16x8 v; } u;
        u.wd[0] = cvtpk(f0.x, f0.y);
        u.wd[1] = cvtpk(f0.z, f0.w);
        u.wd[2] = cvtpk(f1.x, f1.y);
        u.wd[3] = cvtpk(f1.z, f1.w);
        a[ks] = u.v;
    }
    #pragma unroll
    for (int dt = 0; dt < 16; ++dt){
        f32x4 acc = {0.f,0.f,0.f,0.f};
        #pragma unroll
        for (int ks = 0; ks < 8; ++ks){
            bf16x8 b = *(const bf16x8*)(Wp + (size_t)(dt*16 + lr)*256 + ks*32 + lg*8);
            acc = MFMA16(a[ks], b, acc);
        }
        float bv_ = bias[dt*16 + lr];
        int d = dt*16 + lr;
        if (p == 0){
            #pragma unroll
            for (int r = 0; r < 4; ++r){
                int row = r0 + lg*4 + r;
                Out[(size_t)row*256 + d] = cvt1((acc[r] + bv_)*scale);
            }
        } else if (p == 2){
            int row = r0 + lg*4;                  // 4 consecutive s rows
            int bb = row >> 12;
            int s  = row & 4095;
            union { u32 wd[2]; ushort4 v; } u;
            u.wd[0] = cvtpk(acc[0]+bv_, acc[1]+bv_);
            u.wd[1] = cvtpk(acc[2]+bv_, acc[3]+bv_);
            u16* dst = Out + (size_t)bb*1048576 + (size_t)(s>>3)*2048 + d*8 + (s&7);
            *(ushort4*)dst = u.v;
        } else {
            int row = r0 + lg*4;
            int bb = row >> 12;
            int s  = row & 4095;
            u16* dst = Out + (size_t)bb*1048576 + (size_t)(d>>3)*32768 + (size_t)s*8 + (d&7);
            #pragma unroll
            for (int r = 0; r < 4; ++r)
                dst[r*8] = cvt1(acc[r]+bv_);
        }
    }
}

// ---------------- flash attention, kv-split partials ---------------------------------------
// grid 512 (XCD-aware), block 256 = 4 waves x 32 q rows (128 q rows/block)
// Swapped-operand 32x32x16 MFMA: S^T = mfma(K,Q) -> lane owns q=lane&31 column;
// softmax lane-local; P^T packed in regs (shfl_xor 32); PV = mfma(V^T, P^T) = O^T.
// K,V chunk 32 double-buffered in LDS; all frag reads 16B-linear (conflict-free).
#define CH_ROWS 32
#define NCH     32          /* 1024 kv rows per split / 32 */

__global__ __launch_bounds__(256, 2)
void attn_kernel(const u16* __restrict__ Qb, const u16* __restrict__ Kb,
                 const u16* __restrict__ Vt, u16* __restrict__ Opart,
                 float* __restrict__ Mpart, float* __restrict__ Lpart){
    __shared__ char lds[65536];   // K0@0 K1@16384 V0@32768 V1@49152
    int tid = threadIdx.x;
    int w = tid >> 6, lane = tid & 63;
    int q5 = lane & 31, hi = lane >> 5;

    // XCD-aware decode: same (bb,split) combo stays on one XCD for L2 reuse
    int bid = blockIdx.x;
    int xcd = bid & 7;
    int loc = bid >> 3;                 // 0..63
    int combo = xcd*2 + (loc >> 5);     // 0..15
    int qb = loc & 31;
    int bb = combo >> 2;
    int split = combo & 3;
    int qrow0 = qb*128 + w*32;

    const char* Qbyte = (const char*)Qb + (size_t)bb*2097152;
    const char* Kbyte = (const char*)Kb + (size_t)bb*2097152;  // [d>>3][s][d&7]
    const char* Vbyte = (const char*)Vt + (size_t)bb*2097152;  // [s>>3][256][s&7]

    // Q fragments (B operand): lane holds q=q5, depth d = c*16 + hi*8 + j
    bf16x8 qf[16];
    #pragma unroll
    for (int c = 0; c < 16; ++c)
        qf[c] = *(const bf16x8*)(Qbyte + (size_t)(qrow0 + q5)*512 + c*32 + hi*16);

    f32x16 acc[8];
    #pragma unroll
    for (int dt=0;dt<8;++dt)
        #pragma unroll
        for (int i=0;i<16;++i) acc[dt][i] = 0.f;
    float m = -1e30f, ls = 0.f;

    int kv0 = split*1024;

    // ---- prologue: stage K,V chunk 0 into buf 0
    #pragma unroll
    for (int i = 0; i < 4; ++i){
        int o = i*4096 + tid*16;
        async16(Kbyte + ((size_t)(o>>9)*65536 + (size_t)kv0*16 + (o&511)), lds + o);
    }
    #pragma unroll
    for (int i = 0; i < 4; ++i){
        int o = i*4096 + tid*16;
        async16(Vbyte + (size_t)kv0*512 + o, lds + 32768 + o);
    }
    __syncthreads();

    int buf = 0;
    for (int ch = 0; ch < NCH; ++ch){
        // ---- prefetch next chunk into buf^1 (overlaps with compute below)
        if (ch < NCH-1){
            int kvn = kv0 + (ch+1)*CH_ROWS;
            char* Kn = lds + (buf^1)*16384;
            char* Vn = lds + 32768 + (buf^1)*16384;
            #pragma unroll
            for (int i = 0; i < 4; ++i){
                int o = i*4096 + tid*16;
                async16(Kbyte + ((size_t)(o>>9)*65536 + (size_t)kvn*16 + (o&511)), Kn + o);
            }
            #pragma unroll
            for (int i = 0; i < 4; ++i){
                int o = i*4096 + tid*16;
                async16(Vbyte + (size_t)kvn*512 + o, Vn + o);
            }
        }
        char* Kl = lds + buf*16384;
        char* Vl = lds + 32768 + buf*16384;

        // ---- QK^T (swapped): sc = S^T[kv32][q32], depth 256 in 16 chunks
        f32x16 sc;
        #pragma unroll
        for (int i=0;i<16;++i) sc[i] = 0.f;
        __builtin_amdgcn_s_setprio(1);
        #pragma unroll
        for (int c = 0; c < 16; ++c){
            bf16x8 kf = *(const bf16x8*)(Kl + (2*c + hi)*512 + q5*16);
            sc = MFMA32(kf, qf[c], sc);
        }
        __builtin_amdgcn_s_setprio(0);

        // ---- softmax (exp2 domain; defer-max THR=8; all lane-local)
        float lmax = sc[0];
        #pragma unroll
        for (int i=1;i<16;++i) lmax = fmaxf(lmax, sc[i]);
        float pm = fmaxf(lmax, __shfl_xor(lmax, 32));
        if (__any(pm > m + 8.0f)){
            float mn = fmaxf(m, pm);
            float alpha = __builtin_amdgcn_exp2f(m - mn);
            m = mn;
            ls *= alpha;
            #pragma unroll
            for (int dt=0;dt<8;++dt) acc[dt] *= alpha;
        }
        float p[16];
        float rs = 0.f;
        #pragma unroll
        for (int i=0;i<16;++i){ p[i] = __builtin_amdgcn_exp2f(sc[i] - m); rs += p[i]; }
        ls += rs;

        // ---- pack P^T B-frags in registers (kv halves via shfl_xor 32)
        bf16x8 pf[2];
        #pragma unroll
        for (int h=0; h<2; ++h){
            const int o8 = h*8;
            u32 A0 = cvtpk(p[o8+0], p[o8+1]);
            u32 A1 = cvtpk(p[o8+2], p[o8+3]);
            u32 B0 = cvtpk(p[o8+4], p[o8+5]);
            u32 B1 = cvtpk(p[o8+6], p[o8+7]);
            u32 XA0 = __shfl_xor(A0, 32);
            u32 XA1 = __shfl_xor(A1, 32);
            u32 XB0 = __shfl_xor(B0, 32);
            u32 XB1 = __shfl_xor(B1, 32);
            union { u32 wd[4]; bf16x8 v; } u;
            u.wd[0] = hi ? XB0 : A0;
            u.wd[1] = hi ? XB1 : A1;
            u.wd[2] = hi ? B0  : XA0;
            u.wd[3] = hi ? B1  : XA1;
            pf[h] = u.v;
        }

        // ---- PV (swapped): acc[dt] = O^T tiles += mfma(V^T-frag, P^T-frag)
        __builtin_amdgcn_s_setprio(1);
        #pragma unroll
        for (int h=0; h<2; ++h){
            #pragma unroll
            for (int dt=0; dt<8; ++dt){
                bf16x8 vf = *(const bf16x8*)(Vl + (2*h + hi)*4096 + (dt*32 + q5)*16);
                acc[dt] = MFMA32(vf, pf[h], acc[dt]);
            }
        }
        __builtin_amdgcn_s_setprio(0);

        __syncthreads();   // drains prefetch vmcnt + all waves done with buf before overwrite
        buf ^= 1;
    }

    // ---- finalize l (pair sum), write partials (bf16 Opart)
    float l = ls + __shfl_xor(ls, 32);

    size_t pbase = (size_t)(split*4 + bb)*S_SZ*256;
    u16* orow = Opart + pbase + (size_t)(qrow0 + q5)*256;
    #pragma unroll
    for (int dt=0; dt<8; ++dt){
        #pragma unroll
        for (int g=0; g<4; ++g){
            int d0 = dt*32 + g*8 + hi*4;
            union { u32 wd[2]; uint2 v; } u;
            u.wd[0] = cvtpk(acc[dt][4*g+0], acc[dt][4*g+1]);
            u.wd[1] = cvtpk(acc[dt][4*g+2], acc[dt][4*g+3]);
            *(uint2*)(orow + d0) = u.v;
        }
    }
    if (lane < 32){
        int row = qrow0 + q5;
        Mpart[(split*4+bb)*S_SZ + row] = m;
        Lpart[(split*4+bb)*S_SZ + row] = l;
    }
}

// ---------------- combine kv-split partials -------------------------------------------------
__device__ __forceinline__ float bf2f(u16 x){
    union { u32 u; float f; } v; v.u = ((u32)x) << 16; return v.f;
}
__global__ void combine_kernel(const u16* __restrict__ Opart, const float* __restrict__ Mpart,
                               const float* __restrict__ Lpart, float* __restrict__ out){
    int idx = blockIdx.x*256 + threadIdx.x;       // one float4 per thread
    int d4 = (idx & 63)*4;
    int row = idx >> 6;                            // b*4096 + s
    int bb = row >> 12, srow = row & 4095;
    float m[4], lv[4];
    #pragma unroll
    for (int i=0;i<4;++i){
        m[i]  = Mpart[(i*4+bb)*S_SZ + srow];
        lv[i] = Lpart[(i*4+bb)*S_SZ + srow];
    }
    float M = fmaxf(fmaxf(m[0],m[1]), fmaxf(m[2],m[3]));
    float L = 0.f; float wt[4];
    #pragma unroll
    for (int i=0;i<4;++i){ wt[i] = __builtin_amdgcn_exp2f(m[i]-M); L += lv[i]*wt[i]; }
    float inv = 1.f/L;
    float ox=0.f, oy=0.f, oz=0.f, ow=0.f;
    #pragma unroll
    for (int i=0;i<4;++i){
        ushort4 oi = *(const ushort4*)(Opart + (size_t)(i*4+bb)*S_SZ*256 + (size_t)srow*256 + d4);
        ox += bf2f(oi.x)*wt[i]; oy += bf2f(oi.y)*wt[i];
        oz += bf2f(oi.z)*wt[i]; ow += bf2f(oi.w)*wt[i];
    }
    float4 o; o.x = ox*inv; o.y = oy*inv; o.z = oz*inv; o.w = ow*inv;
    *(float4*)(out + (size_t)row*256 + d4) = o;
}

extern "C" void kernel_launch(void* const* d_in, const int* in_sizes, int n_in,
                              void* d_out, int out_size, void* d_ws, size_t ws_size,
                              hipStream_t stream) {
    const float* q_in = (const float*)d_in[0];
    const float* k_in = (const float*)d_in[1];
    const float* v_in = (const float*)d_in[2];
    const float* Wq   = (const float*)d_in[3];
    const float* bq   = (const float*)d_in[4];
    const float* Wk   = (const float*)d_in[5];
    const float* bk   = (const float*)d_in[6];
    const float* Wv   = (const float*)d_in[7];
    const float* bv   = (const float*)d_in[8];

    char* ws = (char*)d_ws;
    u16*  Qb    = (u16*)ws;                         // 8,388,608 B
    u16*  Kb    = (u16*)(ws + 8388608);             // 8,388,608 B
    u16*  Vt    = (u16*)(ws + 16777216);            // 8,388,608 B
    u16*  Wt    = (u16*)(ws + 25165824);            // 393,216 B
    u16*  Opart = (u16*)(ws + 33554432);            // 33,554,432 B (bf16)
    float* Mpart = (float*)(ws + 67108864);         // 262,144 B
    float* Lpart = (float*)(ws + 67371008);         // 262,144 B
    float* out   = (float*)d_out;

    hipLaunchKernelGGL(wconv_kernel,    dim3(768),  dim3(256), 0, stream, Wq, Wk, Wv, Wt);
    hipLaunchKernelGGL(proj_all_kernel, dim3(768),  dim3(256), 0, stream,
                       q_in, k_in, v_in, Wt, bq, bk, bv, Qb, Kb, Vt);
    hipLaunchKernelGGL(attn_kernel,     dim3(512),  dim3(256), 0, stream, Qb, Kb, Vt, Opart, Mpart, Lpart);
    hipLaunchKernelGGL(combine_kernel,  dim3(4096), dim3(256), 0, stream, Opart, Mpart, Lpart, out);
}

// Round 10
// 121.469 us; speedup vs baseline: 2.8089x; 1.2533x over previous
//
#include <hip/hip_runtime.h>
#include <hip/hip_bf16.h>
#include <stdint.h>

#define S_SZ 4096
// (1/sqrt(256)) * log2(e): scores come out in exp2 domain
#define SCL 0.09016844005586937f

typedef short bf16x8 __attribute__((ext_vector_type(8)));
typedef float f32x4 __attribute__((ext_vector_type(4)));
typedef float f32x16 __attribute__((ext_vector_type(16)));
typedef unsigned short u16;
typedef unsigned int u32;

#define MFMA16(a,b,c) __builtin_amdgcn_mfma_f32_16x16x32_bf16(a,b,c,0,0,0)
#define MFMA32(a,b,c) __builtin_amdgcn_mfma_f32_32x32x16_bf16(a,b,c,0,0,0)

// HW packed f32->bf16 (RNE): dst = bf(lo) | bf(hi)<<16
__device__ __forceinline__ u32 cvtpk(float lo, float hi){
    u32 r;
    asm("v_cvt_pk_bf16_f32 %0, %1, %2" : "=v"(r) : "v"(lo), "v"(hi));
    return r;
}
__device__ __forceinline__ u16 cvt1(float a){ return (u16)cvtpk(a, a); }

__device__ __forceinline__ void async16(const void* g, void* l){
    __builtin_amdgcn_global_load_lds(
        (const __attribute__((address_space(1))) unsigned int*)g,
        (__attribute__((address_space(3))) unsigned int*)l, 16, 0, 0);
}

// ---------------- weight transpose + cast: Wt[p][dout][din] = bf16(W[din][dout]) -----------
__global__ void wconv_kernel(const float* __restrict__ Wq, const float* __restrict__ Wk,
                             const float* __restrict__ Wv, u16* __restrict__ Wt){
    int idx = blockIdx.x*256 + threadIdx.x;       // 0..196607
    int p = idx >> 16; int rem = idx & 65535;
    int dout = rem >> 8, din = rem & 255;
    const float* W = (p==0) ? Wq : ((p==1) ? Wk : Wv);
    Wt[idx] = cvt1(W[din*256 + dout]);
}

// ---------------- fused projections: one kernel, 3 slabs of 256 blocks ----------------------
// W-panel staged through LDS in 32KB quarters (pre-swizzled async16 source; XOR reads).
// p=0: Q row-major [row][256], scaled
// p=1: K d-grouped [b][d>>3][s(4096)][d&7]
// p=2: V grouped   [b][s>>3][256][s&7]
__global__ __launch_bounds__(256)
void proj_all_kernel(const float* __restrict__ Xq, const float* __restrict__ Xk,
                     const float* __restrict__ Xv, const u16* __restrict__ Wt,
                     const float* __restrict__ bq, const float* __restrict__ bk,
                     const float* __restrict__ bv,
                     u16* __restrict__ Qb, u16* __restrict__ Kb, u16* __restrict__ Vt){
    __shared__ char wlds[32768];                  // 64 dout rows x 512B (swizzled)
    int tid = threadIdx.x;
    int bid = blockIdx.x;
    int p = bid >> 8;
    const float* X    = (p==0) ? Xq : ((p==1) ? Xk : Xv);
    const float* bias = (p==0) ? bq : ((p==1) ? bk : bv);
    u16* Out          = (p==0) ? Qb : ((p==1) ? Kb : Vt);
    const char* Wbyte = (const char*)Wt + (size_t)p*131072;
    float scale = (p==0) ? SCL : 1.f;

    int w = tid >> 6, lane = tid & 63;
    int lr = lane & 15, lg = lane >> 4;
    int r0 = (bid & 255) * 64 + w * 16;           // this wave's 16 rows

    bf16x8 a[8];
    #pragma unroll
    for (int ks = 0; ks < 8; ++ks){
        const float* src = X + (size_t)(r0 + lr)*256 + ks*32 + lg*8;
        float4 f0 = *(const float4*)src;
        float4 f1 = *(const float4*)(src+4);
        union { u32 wd[4]; bf16x8 v; } u;
        u.wd[0] = cvtpk(f0.x, f0.y);
        u.wd[1] = cvtpk(f0.z, f0.w);
        u.wd[2] = cvtpk(f1.x, f1.y);
        u.wd[3] = cvtpk(f1.z, f1.w);
        a[ks] = u.v;
    }

    for (int qtr = 0; qtr < 4; ++qtr){
        if (qtr) __syncthreads();                 // all waves done reading before overwrite
        const char* wsrc = Wbyte + qtr*32768;
        #pragma unroll
        for (int i = 0; i < 8; ++i){
            int o = i*4096 + tid*16;
            int dout = o >> 9, db = o & 511;
            async16(wsrc + ((dout<<9) | (db ^ ((dout&7)<<4))), wlds + o);
        }
        __syncthreads();                          // staging complete (vmcnt drained)

        #pragma unroll
        for (int dtl = 0; dtl < 4; ++dtl){
            int dt = qtr*4 + dtl;
            int dout_l = dtl*16 + lr;
            f32x4 acc = {0.f,0.f,0.f,0.f};
            #pragma unroll
            for (int ks = 0; ks < 8; ++ks){
                bf16x8 b = *(const bf16x8*)(wlds + dout_l*512 + ((ks*64 + lg*16) ^ ((dout_l&7)<<4)));
                acc = MFMA16(a[ks], b, acc);
            }
            float bv_ = bias[dt*16 + lr];
            int d = dt*16 + lr;
            if (p == 0){
                #pragma unroll
                for (int r = 0; r < 4; ++r){
                    int row = r0 + lg*4 + r;
                    Out[(size_t)row*256 + d] = cvt1((acc[r] + bv_)*scale);
                }
            } else if (p == 2){
                int row = r0 + lg*4;              // 4 consecutive s rows
                int bb = row >> 12;
                int s  = row & 4095;
                union { u32 wd[2]; ushort4 v; } u;
                u.wd[0] = cvtpk(acc[0]+bv_, acc[1]+bv_);
                u.wd[1] = cvtpk(acc[2]+bv_, acc[3]+bv_);
                u16* dst = Out + (size_t)bb*1048576 + (size_t)(s>>3)*2048 + d*8 + (s&7);
                *(ushort4*)dst = u.v;
            } else {
                int row = r0 + lg*4;
                int bb = row >> 12;
                int s  = row & 4095;
                u16* dst = Out + (size_t)bb*1048576 + (size_t)(d>>3)*32768 + (size_t)s*8 + (d&7);
                #pragma unroll
                for (int r = 0; r < 4; ++r)
                    dst[r*8] = cvt1(acc[r]+bv_);
            }
        }
    }
}

// ---------------- flash attention, kv-split partials ---------------------------------------
// grid 512 (XCD-aware), block 256 = 4 waves x 32 q rows (128 q rows/block)
// Swapped-operand 32x32x16 MFMA: S^T = mfma(K,Q) -> lane owns q=lane&31 column;
// softmax lane-local; P^T packed in regs (shfl_xor 32); PV = mfma(V^T, P^T) = O^T.
// K,V chunk 32 double-buffered in LDS; all frag reads 16B-linear (conflict-free).
#define CH_ROWS 32
#define NCH     32          /* 1024 kv rows per split / 32 */

__global__ __launch_bounds__(256, 2)
void attn_kernel(const u16* __restrict__ Qb, const u16* __restrict__ Kb,
                 const u16* __restrict__ Vt, u16* __restrict__ Opart,
                 float* __restrict__ Mpart, float* __restrict__ Lpart){
    __shared__ char lds[65536];   // K0@0 K1@16384 V0@32768 V1@49152
    int tid = threadIdx.x;
    int w = tid >> 6, lane = tid & 63;
    int q5 = lane & 31, hi = lane >> 5;

    // XCD-aware decode: same (bb,split) combo stays on one XCD for L2 reuse
    int bid = blockIdx.x;
    int xcd = bid & 7;
    int loc = bid >> 3;                 // 0..63
    int combo = xcd*2 + (loc >> 5);     // 0..15
    int qb = loc & 31;
    int bb = combo >> 2;
    int split = combo & 3;
    int qrow0 = qb*128 + w*32;

    const char* Qbyte = (const char*)Qb + (size_t)bb*2097152;
    const char* Kbyte = (const char*)Kb + (size_t)bb*2097152;  // [d>>3][s][d&7]
    const char* Vbyte = (const char*)Vt + (size_t)bb*2097152;  // [s>>3][256][s&7]

    // Q fragments (B operand): lane holds q=q5, depth d = c*16 + hi*8 + j
    bf16x8 qf[16];
    #pragma unroll
    for (int c = 0; c < 16; ++c)
        qf[c] = *(const bf16x8*)(Qbyte + (size_t)(qrow0 + q5)*512 + c*32 + hi*16);

    f32x16 acc[8];
    #pragma unroll
    for (int dt=0;dt<8;++dt)
        #pragma unroll
        for (int i=0;i<16;++i) acc[dt][i] = 0.f;
    float m = -1e30f, ls = 0.f;

    int kv0 = split*1024;

    // ---- prologue: stage K,V chunk 0 into buf 0
    #pragma unroll
    for (int i = 0; i < 4; ++i){
        int o = i*4096 + tid*16;
        async16(Kbyte + ((size_t)(o>>9)*65536 + (size_t)kv0*16 + (o&511)), lds + o);
    }
    #pragma unroll
    for (int i = 0; i < 4; ++i){
        int o = i*4096 + tid*16;
        async16(Vbyte + (size_t)kv0*512 + o, lds + 32768 + o);
    }
    __syncthreads();

    int buf = 0;
    for (int ch = 0; ch < NCH; ++ch){
        // ---- prefetch next chunk into buf^1 (overlaps with compute below)
        if (ch < NCH-1){
            int kvn = kv0 + (ch+1)*CH_ROWS;
            char* Kn = lds + (buf^1)*16384;
            char* Vn = lds + 32768 + (buf^1)*16384;
            #pragma unroll
            for (int i = 0; i < 4; ++i){
                int o = i*4096 + tid*16;
                async16(Kbyte + ((size_t)(o>>9)*65536 + (size_t)kvn*16 + (o&511)), Kn + o);
            }
            #pragma unroll
            for (int i = 0; i < 4; ++i){
                int o = i*4096 + tid*16;
                async16(Vbyte + (size_t)kvn*512 + o, Vn + o);
            }
        }
        char* Kl = lds + buf*16384;
        char* Vl = lds + 32768 + buf*16384;

        // ---- QK^T (swapped): sc = S^T[kv32][q32], depth 256 in 16 chunks
        f32x16 sc;
        #pragma unroll
        for (int i=0;i<16;++i) sc[i] = 0.f;
        __builtin_amdgcn_s_setprio(1);
        #pragma unroll
        for (int c = 0; c < 16; ++c){
            bf16x8 kf = *(const bf16x8*)(Kl + (2*c + hi)*512 + q5*16);
            sc = MFMA32(kf, qf[c], sc);
        }
        __builtin_amdgcn_s_setprio(0);

        // ---- pre-issue first PV V-frags: LDS pipe works during softmax VALU
        bf16x8 vfp0 = *(const bf16x8*)(Vl + hi*4096 + q5*16);
        bf16x8 vfp1 = *(const bf16x8*)(Vl + hi*4096 + (32 + q5)*16);

        // ---- softmax (exp2 domain; defer-max THR=8; lane-local; balanced trees)
        float x0 = fmaxf(sc[0], sc[1]),  x1 = fmaxf(sc[2], sc[3]);
        float x2 = fmaxf(sc[4], sc[5]),  x3 = fmaxf(sc[6], sc[7]);
        float x4 = fmaxf(sc[8], sc[9]),  x5 = fmaxf(sc[10], sc[11]);
        float x6 = fmaxf(sc[12], sc[13]),x7 = fmaxf(sc[14], sc[15]);
        float y0 = fmaxf(x0, x1), y1 = fmaxf(x2, x3);
        float y2 = fmaxf(x4, x5), y3 = fmaxf(x6, x7);
        float lmax = fmaxf(fmaxf(y0, y1), fmaxf(y2, y3));
        float pm = fmaxf(lmax, __shfl_xor(lmax, 32));
        if (__any(pm > m + 8.0f)){
            float mn = fmaxf(m, pm);
            float alpha = __builtin_amdgcn_exp2f(m - mn);
            m = mn;
            ls *= alpha;
            #pragma unroll
            for (int dt=0;dt<8;++dt) acc[dt] *= alpha;
        }
        float p[16];
        #pragma unroll
        for (int i=0;i<16;++i) p[i] = __builtin_amdgcn_exp2f(sc[i] - m);
        float s0 = (p[0]+p[1]) + (p[2]+p[3]);
        float s1 = (p[4]+p[5]) + (p[6]+p[7]);
        float s2 = (p[8]+p[9]) + (p[10]+p[11]);
        float s3 = (p[12]+p[13]) + (p[14]+p[15]);
        ls += (s0+s1) + (s2+s3);

        // ---- pack P^T B-frags in registers (kv halves via shfl_xor 32)
        bf16x8 pf[2];
        #pragma unroll
        for (int h=0; h<2; ++h){
            const int o8 = h*8;
            u32 A0 = cvtpk(p[o8+0], p[o8+1]);
            u32 A1 = cvtpk(p[o8+2], p[o8+3]);
            u32 B0 = cvtpk(p[o8+4], p[o8+5]);
            u32 B1 = cvtpk(p[o8+6], p[o8+7]);
            u32 XA0 = __shfl_xor(A0, 32);
            u32 XA1 = __shfl_xor(A1, 32);
            u32 XB0 = __shfl_xor(B0, 32);
            u32 XB1 = __shfl_xor(B1, 32);
            union { u32 wd[4]; bf16x8 v; } u;
            u.wd[0] = hi ? XB0 : A0;
            u.wd[1] = hi ? XB1 : A1;
            u.wd[2] = hi ? B0  : XA0;
            u.wd[3] = hi ? B1  : XA1;
            pf[h] = u.v;
        }

        // ---- PV (swapped): acc[dt] = O^T tiles += mfma(V^T-frag, P^T-frag)
        __builtin_amdgcn_s_setprio(1);
        acc[0] = MFMA32(vfp0, pf[0], acc[0]);
        acc[1] = MFMA32(vfp1, pf[0], acc[1]);
        #pragma unroll
        for (int dt=2; dt<8; ++dt){
            bf16x8 vf = *(const bf16x8*)(Vl + hi*4096 + (dt*32 + q5)*16);
            acc[dt] = MFMA32(vf, pf[0], acc[dt]);
        }
        #pragma unroll
        for (int dt=0; dt<8; ++dt){
            bf16x8 vf = *(const bf16x8*)(Vl + (2 + hi)*4096 + (dt*32 + q5)*16);
            acc[dt] = MFMA32(vf, pf[1], acc[dt]);
        }
        __builtin_amdgcn_s_setprio(0);

        __syncthreads();   // drains prefetch vmcnt + all waves done with buf before overwrite
        buf ^= 1;
    }

    // ---- finalize l (pair sum), write partials (bf16 Opart)
    float l = ls + __shfl_xor(ls, 32);

    size_t pbase = (size_t)(split*4 + bb)*S_SZ*256;
    u16* orow = Opart + pbase + (size_t)(qrow0 + q5)*256;
    #pragma unroll
    for (int dt=0; dt<8; ++dt){
        #pragma unroll
        for (int g=0; g<4; ++g){
            int d0 = dt*32 + g*8 + hi*4;
            union { u32 wd[2]; uint2 v; } u;
            u.wd[0] = cvtpk(acc[dt][4*g+0], acc[dt][4*g+1]);
            u.wd[1] = cvtpk(acc[dt][4*g+2], acc[dt][4*g+3]);
            *(uint2*)(orow + d0) = u.v;
        }
    }
    if (lane < 32){
        int row = qrow0 + q5;
        Mpart[(split*4+bb)*S_SZ + row] = m;
        Lpart[(split*4+bb)*S_SZ + row] = l;
    }
}

// ---------------- combine kv-split partials -------------------------------------------------
__device__ __forceinline__ float bf2f(u16 x){
    union { u32 u; float f; } v; v.u = ((u32)x) << 16; return v.f;
}
__global__ void combine_kernel(const u16* __restrict__ Opart, const float* __restrict__ Mpart,
                               const float* __restrict__ Lpart, float* __restrict__ out){
    int idx = blockIdx.x*256 + threadIdx.x;       // one float4 per thread
    int d4 = (idx & 63)*4;
    int row = idx >> 6;                            // b*4096 + s
    int bb = row >> 12, srow = row & 4095;
    float m[4], lv[4];
    #pragma unroll
    for (int i=0;i<4;++i){
        m[i]  = Mpart[(i*4+bb)*S_SZ + srow];
        lv[i] = Lpart[(i*4+bb)*S_SZ + srow];
    }
    float M = fmaxf(fmaxf(m[0],m[1]), fmaxf(m[2],m[3]));
    float L = 0.f; float wt[4];
    #pragma unroll
    for (int i=0;i<4;++i){ wt[i] = __builtin_amdgcn_exp2f(m[i]-M); L += lv[i]*wt[i]; }
    float inv = 1.f/L;
    float ox=0.f, oy=0.f, oz=0.f, ow=0.f;
    #pragma unroll
    for (int i=0;i<4;++i){
        ushort4 oi = *(const ushort4*)(Opart + (size_t)(i*4+bb)*S_SZ*256 + (size_t)srow*256 + d4);
        ox += bf2f(oi.x)*wt[i]; oy += bf2f(oi.y)*wt[i];
        oz += bf2f(oi.z)*wt[i]; ow += bf2f(oi.w)*wt[i];
    }
    float4 o; o.x = ox*inv; o.y = oy*inv; o.z = oz*inv; o.w = ow*inv;
    *(float4*)(out + (size_t)row*256 + d4) = o;
}

extern "C" void kernel_launch(void* const* d_in, const int* in_sizes, int n_in,
                              void* d_out, int out_size, void* d_ws, size_t ws_size,
                              hipStream_t stream) {
    const float* q_in = (const float*)d_in[0];
    const float* k_in = (const float*)d_in[1];
    const float* v_in = (const float*)d_in[2];
    const float* Wq   = (const float*)d_in[3];
    const float* bq   = (const float*)d_in[4];
    const float* Wk   = (const float*)d_in[5];
    const float* bk   = (const float*)d_in[6];
    const float* Wv   = (const float*)d_in[7];
    const float* bv   = (const float*)d_in[8];

    char* ws = (char*)d_ws;
    u16*  Qb    = (u16*)ws;                         // 8,388,608 B
    u16*  Kb    = (u16*)(ws + 8388608);             // 8,388,608 B
    u16*  Vt    = (u16*)(ws + 16777216);            // 8,388,608 B
    u16*  Wt    = (u16*)(ws + 25165824);            // 393,216 B
    u16*  Opart = (u16*)(ws + 33554432);            // 33,554,432 B (bf16)
    float* Mpart = (float*)(ws + 67108864);         // 262,144 B
    float* Lpart = (float*)(ws + 67371008);         // 262,144 B
    float* out   = (float*)d_out;

    hipLaunchKernelGGL(wconv_kernel,    dim3(768),  dim3(256), 0, stream, Wq, Wk, Wv, Wt);
    hipLaunchKernelGGL(proj_all_kernel, dim3(768),  dim3(256), 0, stream,
                       q_in, k_in, v_in, Wt, bq, bk, bv, Qb, Kb, Vt);
    hipLaunchKernelGGL(attn_kernel,     dim3(512),  dim3(256), 0, stream, Qb, Kb, Vt, Opart, Mpart, Lpart);
    hipLaunchKernelGGL(combine_kernel,  dim3(4096), dim3(256), 0, stream, Opart, Mpart, Lpart, out);
}